// Round 5
// baseline (473.291 us; speedup 1.0000x reference)
//
#include <hip/hip_runtime.h>
#include <stdint.h>

#define M_TOK 256
#define N_OUT 16384
#define K_IN  4096
#define BM 128
#define BN 64
#define BK 64
#define NSTEPS (K_IN / BK)   // 64

typedef short v8s __attribute__((ext_vector_type(8)));
typedef float v16f __attribute__((ext_vector_type(16)));
typedef int   v4i __attribute__((ext_vector_type(4)));
typedef unsigned int uint;

__device__ __forceinline__ unsigned short rne_bf16(float f) {
  uint u = __float_as_uint(f);
  uint r = u + 0x7FFFu + ((u >> 16) & 1u);
  return (unsigned short)(r >> 16);
}
__device__ __forceinline__ float bfbits_to_f(uint h) {
  return __uint_as_float(h << 16);
}
// ints |v| <= 256 are exact in bf16: truncation of the f32 bits suffices
__device__ __forceinline__ uint pack_bf16(float a, float b) {
  return (__float_as_uint(a) >> 16) | (__float_as_uint(b) & 0xffff0000u);
}

// ---------------- kernel 1: exact dual-bf16 split of x (unchanged) ----------------
__global__ __launch_bounds__(256) void cast_kernel(
    const float* __restrict__ x, unsigned short* __restrict__ xhi,
    unsigned short* __restrict__ xlo) {
  const int i = (blockIdx.x * 256 + threadIdx.x) * 4;
  const float4 f = *(const float4*)(x + i);
  float fs[4] = {f.x, f.y, f.z, f.w};
  unsigned short h[4], l[4];
#pragma unroll
  for (int j = 0; j < 4; ++j) {
    h[j] = rne_bf16(fs[j]);
    l[j] = rne_bf16(fs[j] - bfbits_to_f(h[j]));
  }
  *(ushort4*)(xhi + i) = make_ushort4(h[0], h[1], h[2], h[3]);
  *(ushort4*)(xlo + i) = make_ushort4(l[0], l[1], l[2], l[3]);
}

// ---------------- kernel 2: x-direct, K-split dual-bf16 MFMA GEMM ----------------
// BM=128 BN=64 BK=64, 512 blocks x 512 threads (2 blocks/CU, 16 waves/CU).
// 8 waves = 2 m-halves (mp) x 4 k-quarters (kq); each wave owns a 64x64 tile and
// ONE k16-slice per step -> acc[2][2] summed across kq at the end via LDS tree.
// x (bf16 planes, L2/L3-resident) is read DIRECTLY into A-frags (v8s per lane) —
// no LDS staging, no DMA drain. W is staged to LDS (double-buffered 2x8 KiB,
// 256B rows packing n-row pairs, chunk c at pos c^(q&15): measured-zero conflicts).
// One __syncthreads per step; W(t+1) regs issued at top of compute(t).
__global__ __launch_bounds__(512, 4) void gemm_kernel(
    const unsigned short* __restrict__ xhi, const unsigned short* __restrict__ xlo,
    const void* __restrict__ wraw, const float* __restrict__ scales,
    float* __restrict__ out) {
  __shared__ alignas(16) unsigned char smem[65536];  // W dbuf 16K; epilogue 64K
  const int tid = threadIdx.x;
  const int lane = tid & 63;
  const int wid = tid >> 6;

  // --- runtime dtype probe: 64B read, in-bounds under both layouts; uniform result
  const int* wi = (const int*)wraw;
  const signed char* wb = (const signed char*)wraw;
  bool is32 = true;
#pragma unroll
  for (int i = 0; i < 16; ++i) {
    const int v = wi[i];
    is32 = is32 && (v >= -128) && (v <= 127);
  }

  // XCD swizzle: the 2 mb-blocks sharing one W strip are 8 bids apart on one XCD.
  const int bid = blockIdx.x;
  const int logical = (bid & 7) * 64 + (bid >> 3);  // bijective for 512
  const int mb = logical & 1;
  const int nb = logical >> 1;
  const int m0 = mb * BM;
  const int n0 = nb * BN;

  // --- wave roles
  const int mp = wid & 1;    // m-half: rows m0 + mp*64 .. +63
  const int kq = wid >> 1;   // k-quarter: k-slice kq*16 within each BK step
  const int l31 = lane & 31, hi5 = lane >> 5;

  // --- x direct A-frag bases (16B/lane; row = l31, k = kq*16 + hi5*8)
  const size_t xrow = (size_t)(m0 + mp * 64 + l31) * K_IN + (size_t)(kq * 16 + hi5 * 8);
  const unsigned short* pxh = xhi + xrow;
  const unsigned short* pxl = xlo + xrow;

  // --- W staging: thread t owns row t>>3, 16B-bf16-chunk wc = t&7 (coalesced loads)
  const int wrow = tid >> 3, wc = tid & 7;
  const int* w32base = wi + (size_t)(n0 + wrow) * K_IN + (size_t)(wc * 8);
  const signed char* w8base = wb + (size_t)(n0 + wrow) * K_IN + (size_t)(wc * 8);
  const uint wq = (uint)(wrow >> 1);
  const uint waddr = wq * 256u + ((uint)(((wrow & 1) * 8 + wc)) ^ (wq & 15u)) * 16u;

  // --- B-frag LDS read addrs (per nf): n-row wr = nf*32+l31, chunk kq*2+hi5
  uint baddr[2];
#pragma unroll
  for (int nf = 0; nf < 2; ++nf) {
    const int wr = nf * 32 + l31;
    const uint q = (uint)(wr >> 1);
    baddr[nf] = q * 256u + ((uint)((wr & 1) * 8 + kq * 2 + hi5) ^ (q & 15u)) * 16u;
  }

  v16f acc[2][2] = {};
  v4i wt0, wt1;   // int32-path stage regs (8 int32 = one bf16 chunk)
  uint2 w8t;      // int8-path stage regs (8 int8)

  auto load_w = [&](int s) {
    if (is32) {
      wt0 = *(const v4i*)(w32base + (size_t)s * BK);
      wt1 = *(const v4i*)(w32base + (size_t)s * BK + 4);
    } else {
      w8t = *(const uint2*)(w8base + (size_t)s * BK);
    }
  };
  auto conv_w = [&](uint wo) {
    uint d[4];
    if (is32) {
      d[0] = pack_bf16((float)wt0.x, (float)wt0.y);
      d[1] = pack_bf16((float)wt0.z, (float)wt0.w);
      d[2] = pack_bf16((float)wt1.x, (float)wt1.y);
      d[3] = pack_bf16((float)wt1.z, (float)wt1.w);
    } else {
      const signed char* bs = (const signed char*)&w8t;
#pragma unroll
      for (int p = 0; p < 4; ++p)
        d[p] = pack_bf16((float)bs[2 * p], (float)bs[2 * p + 1]);
    }
    v4i wv; wv.x = (int)d[0]; wv.y = (int)d[1]; wv.z = (int)d[2]; wv.w = (int)d[3];
    *(v4i*)(smem + wo + waddr) = wv;
  };

  // ---- prologue: W(0) -> buf0
  load_w(0);
  conv_w(0u);
  __syncthreads();

  // ---- main loop: one barrier per step
  for (int t = 0; t < NSTEPS; ++t) {
    const bool more = (t + 1 < NSTEPS);
    if (more) load_w(t + 1);            // in flight under this step's compute

    const uint rb = (uint)(t & 1) * 8192u;
    const size_t ko = (size_t)t * BK;
    v8s ah0 = *(const v8s*)(pxh + ko);
    v8s al0 = *(const v8s*)(pxl + ko);
    v8s ah1 = *(const v8s*)(pxh + (size_t)32 * K_IN + ko);
    v8s al1 = *(const v8s*)(pxl + (size_t)32 * K_IN + ko);
    v8s b0 = *(const v8s*)(smem + rb + baddr[0]);
    v8s b1 = *(const v8s*)(smem + rb + baddr[1]);

    acc[0][0] = __builtin_amdgcn_mfma_f32_32x32x16_bf16(ah0, b0, acc[0][0], 0, 0, 0);
    acc[0][1] = __builtin_amdgcn_mfma_f32_32x32x16_bf16(ah0, b1, acc[0][1], 0, 0, 0);
    acc[1][0] = __builtin_amdgcn_mfma_f32_32x32x16_bf16(ah1, b0, acc[1][0], 0, 0, 0);
    acc[1][1] = __builtin_amdgcn_mfma_f32_32x32x16_bf16(ah1, b1, acc[1][1], 0, 0, 0);
    acc[0][0] = __builtin_amdgcn_mfma_f32_32x32x16_bf16(al0, b0, acc[0][0], 0, 0, 0);
    acc[0][1] = __builtin_amdgcn_mfma_f32_32x32x16_bf16(al0, b1, acc[0][1], 0, 0, 0);
    acc[1][0] = __builtin_amdgcn_mfma_f32_32x32x16_bf16(al1, b0, acc[1][0], 0, 0, 0);
    acc[1][1] = __builtin_amdgcn_mfma_f32_32x32x16_bf16(al1, b1, acc[1][1], 0, 0, 0);

    if (more) conv_w(rb ^ 8192u);       // wt landed during compute; write buf^1
    __syncthreads();                    // publish buf^1; readers of rb done
  }

  // ---- K-split reduction tree via LDS (regions: ri*16K + frag*4K + q*1K + lane*16)
  auto dump = [&](int ri) {
#pragma unroll
    for (int mf = 0; mf < 2; ++mf)
#pragma unroll
      for (int nf = 0; nf < 2; ++nf)
#pragma unroll
        for (int q = 0; q < 4; ++q) {
          float4 v = make_float4(acc[mf][nf][4 * q], acc[mf][nf][4 * q + 1],
                                 acc[mf][nf][4 * q + 2], acc[mf][nf][4 * q + 3]);
          *(float4*)(smem + ri * 16384 + (mf * 2 + nf) * 4096 + q * 1024 + lane * 16) = v;
        }
  };
  auto take = [&](int ri) {
#pragma unroll
    for (int mf = 0; mf < 2; ++mf)
#pragma unroll
      for (int nf = 0; nf < 2; ++nf)
#pragma unroll
        for (int q = 0; q < 4; ++q) {
          float4 v = *(const float4*)(smem + ri * 16384 + (mf * 2 + nf) * 4096 +
                                      q * 1024 + lane * 16);
          acc[mf][nf][4 * q] += v.x;  acc[mf][nf][4 * q + 1] += v.y;
          acc[mf][nf][4 * q + 2] += v.z;  acc[mf][nf][4 * q + 3] += v.w;
        }
  };
  if (kq >= 2) dump(mp * 2 + (kq - 2));
  __syncthreads();
  if (kq < 2) take(mp * 2 + kq);
  __syncthreads();
  if (kq == 1) dump(mp);
  __syncthreads();
  if (kq == 0) {
    take(mp);
    // C/D: col = lane&31, row = (reg&3) + 8*(reg>>2) + 4*(lane>>5)
#pragma unroll
    for (int nf = 0; nf < 2; ++nf) {
      const int n = n0 + nf * 32 + l31;
      const float scl = scales[n];
#pragma unroll
      for (int mf = 0; mf < 2; ++mf)
#pragma unroll
        for (int reg = 0; reg < 16; ++reg) {
          const int m = m0 + mp * 64 + mf * 32 + (reg & 3) + 8 * (reg >> 2) + 4 * hi5;
          out[(size_t)m * N_OUT + n] = acc[mf][nf][reg] * scl;
        }
    }
  }
}

// ---------------- fallback (workspace too small); also dtype-probed ----------------
__global__ void naive_kernel(const float* __restrict__ x, const void* __restrict__ wraw,
                             const float* __restrict__ scales, float* __restrict__ out) {
  const int* wi = (const int*)wraw;
  bool is32 = true;
  for (int i = 0; i < 16; ++i) { int v = wi[i]; is32 = is32 && v >= -128 && v <= 127; }
  const int idx = blockIdx.x * 256 + threadIdx.x;
  const int m = idx >> 14;
  const int n = idx & (N_OUT - 1);
  const float* xr = x + (size_t)m * K_IN;
  float acc = 0.f;
  if (is32) {
    const int* wr = wi + (size_t)n * K_IN;
    for (int k = 0; k < K_IN; ++k) acc += xr[k] * (float)wr[k];
  } else {
    const signed char* wr = (const signed char*)wraw + (size_t)n * K_IN;
    for (int k = 0; k < K_IN; ++k) acc += xr[k] * (float)wr[k];
  }
  out[idx] = acc * scales[n];
}

extern "C" void kernel_launch(void* const* d_in, const int* in_sizes, int n_in,
                              void* d_out, int out_size, void* d_ws, size_t ws_size,
                              hipStream_t stream) {
  const float* x = (const float*)d_in[0];
  const void* w = d_in[1];  // dtype resolved on-device (int8 vs int32 materialization)
  const float* scales = (const float*)d_in[2];
  float* out = (float*)d_out;
  if (ws_size >= (size_t)4 * 1024 * 1024) {
    unsigned short* xhi = (unsigned short*)d_ws;
    unsigned short* xlo = xhi + (size_t)M_TOK * K_IN;
    cast_kernel<<<(M_TOK * K_IN) / 1024, 256, 0, stream>>>(x, xhi, xlo);
    gemm_kernel<<<512, 512, 0, stream>>>(xhi, xlo, w, scales, out);
  } else {
    naive_kernel<<<(M_TOK * N_OUT) / 256, 256, 0, stream>>>(x, w, scales, out);
  }
}

// Round 6
// 412.756 us; speedup vs baseline: 1.1467x; 1.1467x over previous
//
#include <hip/hip_runtime.h>
#include <stdint.h>

#define M_TOK 256
#define N_OUT 16384
#define K_IN  4096
#define BM 128
#define BN 64
#define BK 64
#define NSTEPS (K_IN / BK)   // 64

#define AS1 __attribute__((address_space(1)))
#define AS3 __attribute__((address_space(3)))

typedef short v8s __attribute__((ext_vector_type(8)));
typedef float v16f __attribute__((ext_vector_type(16)));
typedef int   v4i __attribute__((ext_vector_type(4)));
typedef unsigned int uint;

__device__ __forceinline__ unsigned short rne_bf16(float f) {
  uint u = __float_as_uint(f);
  uint r = u + 0x7FFFu + ((u >> 16) & 1u);
  return (unsigned short)(r >> 16);
}
__device__ __forceinline__ float bfbits_to_f(uint h) {
  return __uint_as_float(h << 16);
}
// ints |v| <= 256 are exact in bf16: truncation of the f32 bits suffices
__device__ __forceinline__ uint pack_bf16(float a, float b) {
  return (__float_as_uint(a) >> 16) | (__float_as_uint(b) & 0xffff0000u);
}

// ---------------- kernel 1: exact dual-bf16 split of x (unchanged) ----------------
__global__ __launch_bounds__(256) void cast_kernel(
    const float* __restrict__ x, unsigned short* __restrict__ xhi,
    unsigned short* __restrict__ xlo) {
  const int i = (blockIdx.x * 256 + threadIdx.x) * 4;
  const float4 f = *(const float4*)(x + i);
  float fs[4] = {f.x, f.y, f.z, f.w};
  unsigned short h[4], l[4];
#pragma unroll
  for (int j = 0; j < 4; ++j) {
    h[j] = rne_bf16(fs[j]);
    l[j] = rne_bf16(fs[j] - bfbits_to_f(h[j]));
  }
  *(ushort4*)(xhi + i) = make_ushort4(h[0], h[1], h[2], h[3]);
  *(ushort4*)(xlo + i) = make_ushort4(l[0], l[1], l[2], l[3]);
}

// ---------------- kernel 2: fully double-buffered dual-bf16 MFMA GEMM ----------------
// r4 structure (the measured-best: BM=128 BN=64 BK=64, 512 blocks x 512 threads,
// 2 blocks/CU, x DMA-staged, W reg->convert->LDS) + full LDS double buffering:
//   xbuf 2 x 32 KiB @0, wbuf 2 x 8 KiB @65536 (80 KiB; 2 blocks = 160 KiB pool).
// ONE __syncthreads per K-step. Per step t: issue x(t+1) gload_lds + W(t+1) reg
// loads FIRST, compute(t) (the hiding window), then convert+ds_write W(t+1), then
// barrier — the drain sees x loads issued a full compute phase earlier.
// All LDS rows 256 B, chunk c of row r at pos c^(r&15): measured-zero conflicts.
__global__ __launch_bounds__(512, 4) void gemm_kernel(
    const unsigned short* __restrict__ xhi, const unsigned short* __restrict__ xlo,
    const void* __restrict__ wraw, const float* __restrict__ scales,
    float* __restrict__ out) {
  __shared__ alignas(16) unsigned char smem[81920];
  const int tid = threadIdx.x;
  const int lane = tid & 63;
  const int wid = tid >> 6;

  // --- runtime dtype probe: 64B read, in-bounds under both layouts; uniform result
  const int* wi = (const int*)wraw;
  const signed char* wb = (const signed char*)wraw;
  bool is32 = true;
#pragma unroll
  for (int i = 0; i < 16; ++i) {
    const int v = wi[i];
    is32 = is32 && (v >= -128) && (v <= 127);
  }

  // XCD swizzle: the 2 mb-blocks sharing one W strip are adjacent in time on one XCD.
  const int bid = blockIdx.x;
  const int logical = (bid & 7) * 64 + (bid >> 3);  // bijective for 512
  const int mb = logical & 1;
  const int nb = logical >> 1;
  const int m0 = mb * BM;
  const int n0 = nb * BN;

  // --- x staging: 4 gload_lds per thread (32 KiB/step); dest linear (base+lane*16),
  // swizzle realized by pre-swizzling the per-lane GLOBAL source chunk.
  const unsigned short* xsrc[4];
  uint xdst[4];
#pragma unroll
  for (int j = 0; j < 4; ++j) {
    const int s = wid * 4 + j;              // 0..31, each stages 4 rows (1 KiB)
    const int r = s * 4 + (lane >> 4);      // row 0..127
    const int c = (lane & 15) ^ (r & 15);   // chunk living at LDS pos lane&15
    xsrc[j] = (c >= 8 ? xlo : xhi) + (size_t)(m0 + r) * K_IN + (size_t)((c & 7) * 8);
    xdst[j] = (uint)(s * 1024);
  }

  // --- W staging: thread t owns row t>>3 (0..63), 32B span wc = t&7 (coalesced).
  const int wrow = tid >> 3, wc = tid & 7;
  const int* w32base = wi + (size_t)(n0 + wrow) * K_IN + (size_t)(wc * 8);
  const signed char* w8base = wb + (size_t)(n0 + wrow) * K_IN + (size_t)(wc * 8);
  // LDS target: one ds_write_b128 per thread; LDS row q packs n-rows 2q|2q+1
  const uint wq = (uint)(wrow >> 1);
  const uint wchunk = (uint)((wrow & 1) * 8 + wc);
  const uint waddr = wq * 256u + ((wchunk ^ (wq & 15u)) << 4);

  // --- compute descriptors (mfma_f32_32x32x16_bf16; verified layouts)
  const int l31 = lane & 31, hi5 = lane >> 5;
  const int wm = (wid & 3) * 32;        // 4 m-waves
  const int wn = (wid >> 2) * 32;       // 2 n-waves
  const uint arow = (uint)((wm + l31) * 256);
  const uint ax = (uint)((wm + l31) & 15);
  const int wr = wn + l31;              // W n-row 0..63
  const uint bq = (uint)(wr >> 1);
  const uint bbase = bq * 256u;
  const uint bsel = (uint)((wr & 1) * 8);
  const uint bx = bq & 15u;

  v16f acc = {};
  v4i wt0, wt1;  // W stage regs (8 VGPR; int8 path uses wt0.x/.y only)

  auto stage_x = [&](int s, uint xb) {
#pragma unroll
    for (int j = 0; j < 4; ++j)
      __builtin_amdgcn_global_load_lds(
          (const AS1 void*)(xsrc[j] + (size_t)s * BK),
          (AS3 void*)(smem + xb + xdst[j]), 16, 0, 0);
  };
  auto load_w = [&](int s) {
    if (is32) {
      wt0 = *(const v4i*)(w32base + (size_t)s * BK);
      wt1 = *(const v4i*)(w32base + (size_t)s * BK + 4);
    } else {
      const uint2 u = *(const uint2*)(w8base + (size_t)s * BK);
      wt0.x = (int)u.x; wt0.y = (int)u.y;
    }
  };
  auto conv_w = [&](uint wo) {
    uint d[4];
    if (is32) {
      d[0] = pack_bf16((float)wt0.x, (float)wt0.y);
      d[1] = pack_bf16((float)wt0.z, (float)wt0.w);
      d[2] = pack_bf16((float)wt1.x, (float)wt1.y);
      d[3] = pack_bf16((float)wt1.z, (float)wt1.w);
    } else {
      const signed char* bs = (const signed char*)&wt0;  // 8 bytes in wt0.x/.y
#pragma unroll
      for (int p = 0; p < 4; ++p)
        d[p] = pack_bf16((float)bs[2 * p], (float)bs[2 * p + 1]);
    }
    v4i wv; wv.x = (int)d[0]; wv.y = (int)d[1]; wv.z = (int)d[2]; wv.w = (int)d[3];
    *(v4i*)(smem + wo + waddr) = wv;
  };

  // ---- prologue: x(0)+W(0) -> buffer 0
  stage_x(0, 0u);
  load_w(0);
  conv_w(65536u);      // auto-waits wt
  __syncthreads();     // drains x(0) DMA (one-time cost)

  // ---- main loop: ONE barrier per step
  for (int t = 0; t < NSTEPS; ++t) {
    const uint xb = (uint)(t & 1) * 32768u;
    const uint wo = 65536u + (uint)(t & 1) * 8192u;
    const bool more = (t + 1 < NSTEPS);
    if (more) {
      stage_x(t + 1, xb ^ 32768u);   // DMA into the other x buffer
      load_w(t + 1);                 // W regs in flight under compute
    }
    __builtin_amdgcn_sched_barrier(0);  // pin issues above compute

#pragma unroll
    for (int kc = 0; kc < 4; ++kc) {
      const uint ch = (uint)(kc * 2 + hi5);
      v8s ah = *(const v8s*)(smem + xb + arow + ((ch ^ ax) << 4));
      v8s al = *(const v8s*)(smem + xb + arow + (((ch + 8u) ^ ax) << 4));
      v8s b  = *(const v8s*)(smem + wo + bbase + (((bsel + ch) ^ bx) << 4));
      acc = __builtin_amdgcn_mfma_f32_32x32x16_bf16(ah, b, acc, 0, 0, 0);
      acc = __builtin_amdgcn_mfma_f32_32x32x16_bf16(al, b, acc, 0, 0, 0);
    }

    if (more) conv_w(wo ^ 8192u);    // wt landed during compute; write buf^1
    __syncthreads();                 // publish t+1; readers of t done
  }

  // ---- epilogue: C/D col = lane&31, row = (reg&3) + 8*(reg>>2) + 4*(lane>>5)
  const int n = n0 + wn + l31;
  const float scl = scales[n];
#pragma unroll
  for (int reg = 0; reg < 16; ++reg) {
    const int m = m0 + wm + (reg & 3) + 8 * (reg >> 2) + 4 * hi5;
    out[(size_t)m * N_OUT + n] = acc[reg] * scl;
  }
}

// ---------------- fallback (workspace too small); also dtype-probed ----------------
__global__ void naive_kernel(const float* __restrict__ x, const void* __restrict__ wraw,
                             const float* __restrict__ scales, float* __restrict__ out) {
  const int* wi = (const int*)wraw;
  bool is32 = true;
  for (int i = 0; i < 16; ++i) { int v = wi[i]; is32 = is32 && v >= -128 && v <= 127; }
  const int idx = blockIdx.x * 256 + threadIdx.x;
  const int m = idx >> 14;
  const int n = idx & (N_OUT - 1);
  const float* xr = x + (size_t)m * K_IN;
  float acc = 0.f;
  if (is32) {
    const int* wr = wi + (size_t)n * K_IN;
    for (int k = 0; k < K_IN; ++k) acc += xr[k] * (float)wr[k];
  } else {
    const signed char* wr = (const signed char*)wraw + (size_t)n * K_IN;
    for (int k = 0; k < K_IN; ++k) acc += xr[k] * (float)wr[k];
  }
  out[idx] = acc * scales[n];
}

extern "C" void kernel_launch(void* const* d_in, const int* in_sizes, int n_in,
                              void* d_out, int out_size, void* d_ws, size_t ws_size,
                              hipStream_t stream) {
  const float* x = (const float*)d_in[0];
  const void* w = d_in[1];  // dtype resolved on-device (int8 vs int32 materialization)
  const float* scales = (const float*)d_in[2];
  float* out = (float*)d_out;
  if (ws_size >= (size_t)4 * 1024 * 1024) {
    unsigned short* xhi = (unsigned short*)d_ws;
    unsigned short* xlo = xhi + (size_t)M_TOK * K_IN;
    cast_kernel<<<(M_TOK * K_IN) / 1024, 256, 0, stream>>>(x, xhi, xlo);
    gemm_kernel<<<512, 512, 0, stream>>>(xhi, xlo, w, scales, out);
  } else {
    naive_kernel<<<(M_TOK * N_OUT) / 256, 256, 0, stream>>>(x, w, scales, out);
  }
}